// Round 4
// baseline (98.201 us; speedup 1.0000x reference)
//
#include <hip/hip_runtime.h>

// y[g,k,n,m] = sum_{i,j} w[i,k,j] * r[m+j],  r[p] = x[g,i,n,(p-2)%7] for
// p in 1..7 else 0;  out[g,k,(n+1)%7,m] = y[g,k,n,m].  (shift==1 folded in)
//
// R4: FUSED single kernel. 512 producer blocks (kc x ic) write fp32 partials
// to d_ws with plain stores, then release a per-(kc,ic) flag (agent-scope
// atomic, MAGIC value -> correct for any initial flag contents; harness
// poisons ws to 0xAAAAAAAA). 32 reducer blocks (one per kc) spin-acquire
// their 16 flags and reduce 16 partial slabs -> out. All 544 blocks are
// co-resident (27.6 KB LDS -> 5 blocks/CU), so spinning cannot deadlock.
// Removes stage-2 launch + full inter-kernel serialization vs R3.

#define NKC 32   // k-chunks
#define KC  16   // k per chunk
#define NIC 16   // i-chunks
#define IC  32   // i per chunk
#define OUT_N (2 * 512 * 7 * 7)   // 50176
#define MAGIC 0x13579BDFu

__global__ __launch_bounds__(256) void conv_fused(
    const float* __restrict__ x,        // (1024, 7, 7) = (g*512+i, n, m)
    const float* __restrict__ w,        // (512, 512, 3) = (i, k, j)
    float* __restrict__ out,            // (1024, 7, 7)
    float* __restrict__ partial,        // ws: (NIC, OUT_N)
    unsigned int* __restrict__ flags)   // ws: (NKC, NIC)
{
    // x rows pre-rolled/padded: x_s[g][iL][n][p]; p=1..7 data, p=0,8 zero.
    __shared__ __align__(16) float x_s[2][IC][7][12];
    __shared__ __align__(16) float w_s[IC * KC * 3];

    const int tid = threadIdx.x;
    const int b   = blockIdx.x;

    if (b < NKC * NIC) {
        // ================= producer =================
        const int kc = b % NKC;
        const int ic = b / NKC;
        const int i0 = ic * IC;

        // w slice as float4: row iL = 48 contiguous floats, 16B-aligned
        #pragma unroll
        for (int f = tid; f < IC * KC * 3 / 4; f += 256) {
            const int iL = f / 12;
            const int c4 = f % 12;
            ((float4*)w_s)[f] =
                ((const float4*)(w + (size_t)(i0 + iL) * 1536 + kc * (KC * 3)))[c4];
        }

        // zero ONLY the pad slots actually read (mm = 0 and 8)
        #pragma unroll
        for (int f = tid; f < 2 * IC * 7; f += 256) {
            const int g  = f / (IC * 7);
            const int r  = f % (IC * 7);
            const int iL = r / 7;
            const int n  = r % 7;
            x_s[g][iL][n][0] = 0.f;
            x_s[g][iL][n][8] = 0.f;
        }

        // coalesced x load; width-roll folded into LDS write index:
        // x[g, i0+iL, n, m] -> x_s[g][iL][n][(m+1)%7 + 1]
        #pragma unroll
        for (int f = tid; f < 2 * IC * 49; f += 256) {
            const int g  = f / (IC * 49);
            const int r  = f % (IC * 49);
            const int iL = r / 49;
            const int q  = r % 49;
            const int n  = q / 7;
            const int m  = q % 7;
            x_s[g][iL][n][(m + 1) % 7 + 1] =
                x[(size_t)g * 25088 + (size_t)i0 * 49 + r];
        }
        __syncthreads();

        if (tid < KC * 14) {
            const int kL = tid % KC;
            const int gn = tid / KC;
            const int g  = gn & 1;
            const int n  = gn >> 1;

            float acc0 = 0.f, acc1 = 0.f, acc2 = 0.f, acc3 = 0.f;
            float acc4 = 0.f, acc5 = 0.f, acc6 = 0.f;

            #pragma unroll 4
            for (int iL = 0; iL < IC; ++iL) {
                const float* wr = &w_s[iL * (KC * 3) + kL * 3];
                const float w0 = wr[0], w1 = wr[1], w2 = wr[2];
                const float* r = &x_s[g][iL][n][0];
                const float4 ra = *(const float4*)(r);
                const float4 rb = *(const float4*)(r + 4);
                const float  r8 = r[8];
                acc0 += w0 * ra.x + w1 * ra.y + w2 * ra.z;
                acc1 += w0 * ra.y + w1 * ra.z + w2 * ra.w;
                acc2 += w0 * ra.z + w1 * ra.w + w2 * rb.x;
                acc3 += w0 * ra.w + w1 * rb.x + w2 * rb.y;
                acc4 += w0 * rb.x + w1 * rb.y + w2 * rb.z;
                acc5 += w0 * rb.y + w1 * rb.z + w2 * rb.w;
                acc6 += w0 * rb.z + w1 * rb.w + w2 * r8;
            }

            const int nOut = (n + 1) % 7;   // final height roll
            const int k    = kc * KC + kL;
            float* pp = partial + (size_t)ic * OUT_N
                      + (((g * 512 + k) * 7) + nOut) * 7;
            pp[0] = acc0; pp[1] = acc1; pp[2] = acc2; pp[3] = acc3;
            pp[4] = acc4; pp[5] = acc5; pp[6] = acc6;
        }

        // barrier drains vmcnt for ALL threads' stores, then one release
        __syncthreads();
        if (tid == 0) {
            __threadfence();   // agent-scope: writeback L2 so L3 is fresh
            __hip_atomic_store(&flags[kc * NIC + ic], MAGIC,
                               __ATOMIC_RELEASE, __HIP_MEMORY_SCOPE_AGENT);
        }
    } else {
        // ================= reducer (one block per kc) =================
        const int kc = b - NKC * NIC;
        if (tid < NIC) {
            while (__hip_atomic_load(&flags[kc * NIC + tid],
                                     __ATOMIC_ACQUIRE,
                                     __HIP_MEMORY_SCOPE_AGENT) != MAGIC) {
                __builtin_amdgcn_s_sleep(1);
            }
        }
        __syncthreads();

        // outputs for this kc: two contiguous runs (g=0,1) of 784 floats
        // starting at (g*512 + kc*KC)*49 -- float4-aligned, 196 float4 each.
        const float4* partial4 = (const float4*)partial;
        float4*       out4     = (float4*)out;
        #pragma unroll
        for (int f = tid; f < 2 * 196; f += 256) {
            const int g  = f / 196;
            const int c4 = f % 196;
            const size_t off4 = (size_t)(g * 512 + kc * KC) * 49 / 4 + c4;
            float4 s = partial4[off4];
            #pragma unroll
            for (int c = 1; c < NIC; ++c) {
                const float4 p = partial4[(size_t)c * (OUT_N / 4) + off4];
                s.x += p.x; s.y += p.y; s.z += p.z; s.w += p.w;
            }
            out4[off4] = s;
        }
    }
}

// Fallback (ws too small): atomic accumulate straight into out.
__global__ __launch_bounds__(256) void conv_atomic(
    const float* __restrict__ x, const float* __restrict__ w,
    float* __restrict__ out)
{
    __shared__ __align__(16) float x_s[2][IC][7][12];
    __shared__ float w_s[IC][KC * 3];
    const int tid = threadIdx.x;
    const int kc  = blockIdx.x % NKC;
    const int ic  = blockIdx.x / NKC;
    const int i0  = ic * IC;
    for (int f = tid; f < IC * KC * 3; f += 256) {
        const int iL = f / (KC * 3), r = f % (KC * 3);
        w_s[iL][r] = w[(i0 + iL) * (512 * 3) + kc * (KC * 3) + r];
    }
    for (int f = tid; f < 2 * IC * 7 * 12; f += 256) {
        const int mm = f % 12; int rest = f / 12;
        const int n = rest % 7; rest /= 7;
        const int iL = rest % IC; const int g = rest / IC;
        float v = 0.f;
        if (mm >= 1 && mm <= 7) v = x[((g * 512 + i0 + iL) * 7 + n) * 7 + (mm + 5) % 7];
        x_s[g][iL][n][mm] = v;
    }
    __syncthreads();
    if (tid < KC * 14) {
        const int kL = tid % KC, gn = tid / KC, g = gn & 1, n = gn >> 1;
        float a[7] = {0,0,0,0,0,0,0};
        for (int iL = 0; iL < IC; ++iL) {
            const float* wr = &w_s[iL][kL * 3];
            const float w0 = wr[0], w1 = wr[1], w2 = wr[2];
            const float* r = &x_s[g][iL][n][0];
            for (int m = 0; m < 7; ++m)
                a[m] += w0 * r[m] + w1 * r[m + 1] + w2 * r[m + 2];
        }
        float* op = out + (((g * 512 + kc * KC + kL) * 7) + (n + 1) % 7) * 7;
        for (int m = 0; m < 7; ++m) atomicAdd(op + m, a[m]);
    }
}

extern "C" void kernel_launch(void* const* d_in, const int* in_sizes, int n_in,
                              void* d_out, int out_size, void* d_ws, size_t ws_size,
                              hipStream_t stream) {
    const float* x = (const float*)d_in[0];
    const float* w = (const float*)d_in[1];
    float* out = (float*)d_out;

    const size_t part_bytes = (size_t)NIC * OUT_N * sizeof(float);      // 3.2 MB
    const size_t flag_bytes = (size_t)NKC * NIC * sizeof(unsigned int); // 2 KB

    if (ws_size >= part_bytes + flag_bytes) {
        float* partial = (float*)d_ws;
        unsigned int* flags = (unsigned int*)((char*)d_ws + part_bytes);
        conv_fused<<<dim3(NKC * NIC + NKC), dim3(256), 0, stream>>>(
            x, w, out, partial, flags);
    } else {
        hipMemsetAsync(out, 0, (size_t)out_size * sizeof(float), stream);
        conv_atomic<<<dim3(NKC * NIC), dim3(256), 0, stream>>>(x, w, out);
    }
}

// Round 5
// 70.006 us; speedup vs baseline: 1.4027x; 1.4027x over previous
//
#include <hip/hip_runtime.h>

// y[g,k,n,m] = sum_{i,j} w[i,k,j] * r[m+j],  r[p] = x[g,i,n,(p-2)%7] for
// p in 1..7 else 0;  out[g,k,(n+1)%7,m] = y[g,k,n,m].  (shift==1 folded in)
//
// R5: revert R4's fused producer-consumer (agent-scope fences + spin-acquire
// thrashed L2: FETCH 2.85->4.5MB, WRITE 7.5MB, 46us). Back to two-kernel
// split-K, tuned: NIC 32->8 (256 blocks = 1/CU; partial traffic 6.4->1.6MB),
// single __syncthreads in stage-1, float4 w staging, float4 stage-2.

#define NKC 32   // k-chunks
#define KC  16   // k per chunk
#define NIC 8    // i-chunks
#define IC  64   // i per chunk
#define OUT_N (2 * 512 * 7 * 7)   // 50176

__global__ __launch_bounds__(256) void conv_stage1(
    const float* __restrict__ x,      // (1024, 7, 7) = (g*512+i, n, m)
    const float* __restrict__ w,      // (512, 512, 3) = (i, k, j)
    float* __restrict__ partial)      // (NIC, OUT_N)
{
    // x rows pre-rolled/padded: x_s[g][iL][n][p]; p=1..7 data, p=0,8 zero.
    __shared__ __align__(16) float x_s[2][IC][7][12];   // 43.0 KB
    __shared__ __align__(16) float w_s[IC * KC * 3];    // 12.3 KB

    const int tid = threadIdx.x;
    const int kc  = blockIdx.x % NKC;
    const int ic  = blockIdx.x / NKC;
    const int i0  = ic * IC;

    // ---- w slice as float4: row iL = 48 contiguous floats, 16B-aligned ----
    #pragma unroll
    for (int f = tid; f < IC * KC * 3 / 4; f += 256) {
        const int iL = f / 12;
        const int c4 = f % 12;
        ((float4*)w_s)[f] =
            ((const float4*)(w + (size_t)(i0 + iL) * 1536 + kc * (KC * 3)))[c4];
    }

    // ---- zero only the pad slots actually read (mm = 0 and 8) ----
    #pragma unroll
    for (int f = tid; f < 2 * IC * 7; f += 256) {
        const int g  = f / (IC * 7);
        const int r  = f % (IC * 7);
        const int iL = r / 7;
        const int n  = r % 7;
        x_s[g][iL][n][0] = 0.f;
        x_s[g][iL][n][8] = 0.f;
    }

    // ---- coalesced x load; width-roll folded into LDS write index ----
    // x[g, i0+iL, n, m] -> x_s[g][iL][n][(m+1)%7 + 1]
    #pragma unroll
    for (int e = tid; e < 2 * IC * 49; e += 256) {
        const int g  = e / (IC * 49);
        const int r  = e % (IC * 49);
        const int iL = r / 49;
        const int q  = r % 49;
        const int n  = q / 7;
        const int m  = q % 7;
        const int mm = (m == 6) ? 1 : (m + 2);
        x_s[g][iL][n][mm] = x[(size_t)g * 25088 + (size_t)i0 * 49 + r];
    }
    __syncthreads();

    // ---- compute: thread = (kL, g, n), 224 active of 256 ----
    if (tid < KC * 14) {
        const int kL = tid % KC;
        const int gn = tid / KC;
        const int g  = gn & 1;
        const int n  = gn >> 1;

        float acc0 = 0.f, acc1 = 0.f, acc2 = 0.f, acc3 = 0.f;
        float acc4 = 0.f, acc5 = 0.f, acc6 = 0.f;

        #pragma unroll 4
        for (int iL = 0; iL < IC; ++iL) {
            const float* wr = &w_s[iL * (KC * 3) + kL * 3];
            const float w0 = wr[0], w1 = wr[1], w2 = wr[2];
            const float* r = &x_s[g][iL][n][0];
            const float4 ra = *(const float4*)(r);
            const float4 rb = *(const float4*)(r + 4);
            const float  r8 = r[8];
            acc0 += w0 * ra.x + w1 * ra.y + w2 * ra.z;
            acc1 += w0 * ra.y + w1 * ra.z + w2 * ra.w;
            acc2 += w0 * ra.z + w1 * ra.w + w2 * rb.x;
            acc3 += w0 * ra.w + w1 * rb.x + w2 * rb.y;
            acc4 += w0 * rb.x + w1 * rb.y + w2 * rb.z;
            acc5 += w0 * rb.y + w1 * rb.z + w2 * rb.w;
            acc6 += w0 * rb.z + w1 * rb.w + w2 * r8;
        }

        const int nOut = (n + 1) % 7;   // final height roll
        const int k    = kc * KC + kL;
        float* pp = partial + (size_t)ic * OUT_N
                  + (((g * 512 + k) * 7) + nOut) * 7;
        pp[0] = acc0; pp[1] = acc1; pp[2] = acc2; pp[3] = acc3;
        pp[4] = acc4; pp[5] = acc5; pp[6] = acc6;
    }
}

__global__ __launch_bounds__(256) void conv_stage2(
    const float4* __restrict__ partial, float4* __restrict__ out)
{
    const int o = blockIdx.x * 256 + threadIdx.x;   // OUT_N/4 = 49*256 exactly
    float4 s = partial[o];
    #pragma unroll
    for (int c = 1; c < NIC; ++c) {
        const float4 p = partial[(size_t)c * (OUT_N / 4) + o];
        s.x += p.x; s.y += p.y; s.z += p.z; s.w += p.w;
    }
    out[o] = s;
}

// Fallback (ws too small): atomic accumulate straight into out.
__global__ __launch_bounds__(256) void conv_atomic(
    const float* __restrict__ x, const float* __restrict__ w,
    float* __restrict__ out)
{
    constexpr int ICA = 32;
    __shared__ __align__(16) float x_s[2][ICA][7][12];
    __shared__ float w_s[ICA][KC * 3];
    const int tid = threadIdx.x;
    const int kc  = blockIdx.x % NKC;
    const int ic  = blockIdx.x / NKC;
    const int i0  = ic * ICA;
    for (int f = tid; f < ICA * KC * 3; f += 256) {
        const int iL = f / (KC * 3), r = f % (KC * 3);
        w_s[iL][r] = w[(i0 + iL) * (512 * 3) + kc * (KC * 3) + r];
    }
    for (int f = tid; f < 2 * ICA * 7 * 12; f += 256) {
        const int mm = f % 12; int rest = f / 12;
        const int n = rest % 7; rest /= 7;
        const int iL = rest % ICA; const int g = rest / ICA;
        float v = 0.f;
        if (mm >= 1 && mm <= 7) v = x[((g * 512 + i0 + iL) * 7 + n) * 7 + (mm + 5) % 7];
        x_s[g][iL][n][mm] = v;
    }
    __syncthreads();
    if (tid < KC * 14) {
        const int kL = tid % KC, gn = tid / KC, g = gn & 1, n = gn >> 1;
        float a[7] = {0,0,0,0,0,0,0};
        for (int iL = 0; iL < ICA; ++iL) {
            const float* wr = &w_s[iL][kL * 3];
            const float w0 = wr[0], w1 = wr[1], w2 = wr[2];
            const float* r = &x_s[g][iL][n][0];
            for (int m = 0; m < 7; ++m)
                a[m] += w0 * r[m] + w1 * r[m + 1] + w2 * r[m + 2];
        }
        float* op = out + (((g * 512 + kc * KC + kL) * 7) + (n + 1) % 7) * 7;
        for (int m = 0; m < 7; ++m) atomicAdd(op + m, a[m]);
    }
}

extern "C" void kernel_launch(void* const* d_in, const int* in_sizes, int n_in,
                              void* d_out, int out_size, void* d_ws, size_t ws_size,
                              hipStream_t stream) {
    const float* x = (const float*)d_in[0];
    const float* w = (const float*)d_in[1];
    float* out = (float*)d_out;
    float* ws  = (float*)d_ws;

    const size_t need = (size_t)NIC * OUT_N * sizeof(float);  // 1.6 MB

    if (ws_size >= need) {
        conv_stage1<<<dim3(NKC * NIC), dim3(256), 0, stream>>>(x, w, ws);
        conv_stage2<<<dim3(OUT_N / 4 / 256), dim3(256), 0, stream>>>(
            (const float4*)ws, (float4*)out);
    } else {
        hipMemsetAsync(out, 0, (size_t)out_size * sizeof(float), stream);
        conv_atomic<<<dim3(NKC * 16), dim3(256), 0, stream>>>(x, w, out);
    }
}

// Round 6
// 67.196 us; speedup vs baseline: 1.4614x; 1.0418x over previous
//
#include <hip/hip_runtime.h>

// y[g,k,n,m] = sum_{i,j} w[i,k,j] * r[m+j],  r[p] = x[g,i,n,(p-2)%7] for
// p in 1..7 else 0;  out[g,k,(n+1)%7,m] = y[g,k,n,m].  (shift==1 folded in)
//
// R6: SINGLE kernel, no split-K, no workspace, no atomics, no out-memset.
// R3 vs R5 were neutral under 4x grid/LDS changes -> dispatch count + fixed
// overhead dominate. Grid = 32 kc x 14 (g,n) = 448 blocks; each block owns
// out[g, kc*16..+15, (n+1)%7, :] fully (sums all 512 i). kc = bid%32 so the
// 14 blocks sharing a w-slab land on one XCD (bid%8 == kc%8) -> slab hits
// that XCD's L2 after first touch. x row staged in LDS with the width-roll
// folded in; row addressing swizzled (+4 floats per 32 rows) to break the
// 4-way bank conflict from the 384-float inter-ic row distance (zero cost:
// swizzle term is constant per thread). i-reduction: shfl_xor(16,32) + tiny
// LDS tree across the 4 waves.

#define NKC 32
#define KC  16

__device__ __forceinline__ int xrow(int i) {   // swizzled LDS row offset
    return i * 12 + ((i >> 5) << 2);
}

__global__ __launch_bounds__(256) void conv_one(
    const float* __restrict__ x,   // (1024, 7, 7) = (g*512+i, n, m)
    const float* __restrict__ w,   // (512, 512, 3) = (i, k, j)
    float* __restrict__ out)       // (1024, 7, 7)
{
    // 512 rows x 12 floats (+ swizzle pad): r[p]=x[g,i,n,(p-2)%7], p=1..7
    __shared__ __align__(16) float x_s[512 * 12 + 64];
    __shared__ float red[4][16][7];

    const int b   = blockIdx.x;        // 448
    const int kc  = b & 31;            // same-kc blocks -> same XCD (bid%8)
    const int gn  = b >> 5;            // 0..13
    const int g   = gn & 1;
    const int n   = gn >> 1;
    const int tid = threadIdx.x;
    const int kL  = tid & 15;
    const int ic  = tid >> 4;          // 0..15, 32 i each

    // ---- stage x[g, :, n, :] with width-roll folded in ----
    const float* xg = x + (size_t)g * 25088 + n * 7;   // [i*49 + m]
    #pragma unroll
    for (int e = tid; e < 512 * 7; e += 256) {
        const int i  = e / 7;
        const int m  = e % 7;
        const int mm = (m == 6) ? 1 : (m + 2);          // (m+2) mod 7 -> 1..7
        x_s[xrow(i) + mm] = xg[i * 49 + m];
    }
    #pragma unroll
    for (int i = tid; i < 512; i += 256) {              // zero pads p=0,8
        x_s[xrow(i) + 0] = 0.f;
        x_s[xrow(i) + 8] = 0.f;
    }
    __syncthreads();

    // ---- accumulate over this thread's 32 i values ----
    const int k = kc * KC + kL;
    const float* wp = w + (size_t)(ic * 32) * 1536 + k * 3;
    const float* xr = &x_s[xrow(ic * 32)];              // advance 12/iter

    float a0 = 0.f, a1 = 0.f, a2 = 0.f, a3 = 0.f, a4 = 0.f, a5 = 0.f, a6 = 0.f;

    #pragma unroll 4
    for (int ii = 0; ii < 32; ++ii) {
        const float w0 = wp[0], w1 = wp[1], w2 = wp[2];
        wp += 1536;
        const float4 ra = *(const float4*)(xr);         // r[0..3]
        const float4 rb = *(const float4*)(xr + 4);     // r[4..7]
        const float  r8 = xr[8];
        xr += 12;
        a0 += w0 * ra.x + w1 * ra.y + w2 * ra.z;
        a1 += w0 * ra.y + w1 * ra.z + w2 * ra.w;
        a2 += w0 * ra.z + w1 * ra.w + w2 * rb.x;
        a3 += w0 * ra.w + w1 * rb.x + w2 * rb.y;
        a4 += w0 * rb.x + w1 * rb.y + w2 * rb.z;
        a5 += w0 * rb.y + w1 * rb.z + w2 * rb.w;
        a6 += w0 * rb.z + w1 * rb.w + w2 * r8;
    }

    // ---- reduce the 4 ic-groups within each wave (lane bits 4,5) ----
    a0 += __shfl_xor(a0, 16); a0 += __shfl_xor(a0, 32);
    a1 += __shfl_xor(a1, 16); a1 += __shfl_xor(a1, 32);
    a2 += __shfl_xor(a2, 16); a2 += __shfl_xor(a2, 32);
    a3 += __shfl_xor(a3, 16); a3 += __shfl_xor(a3, 32);
    a4 += __shfl_xor(a4, 16); a4 += __shfl_xor(a4, 32);
    a5 += __shfl_xor(a5, 16); a5 += __shfl_xor(a5, 32);
    a6 += __shfl_xor(a6, 16); a6 += __shfl_xor(a6, 32);

    const int wave = tid >> 6;
    if ((tid & 63) < 16) {
        red[wave][kL][0] = a0; red[wave][kL][1] = a1; red[wave][kL][2] = a2;
        red[wave][kL][3] = a3; red[wave][kL][4] = a4; red[wave][kL][5] = a5;
        red[wave][kL][6] = a6;
    }
    __syncthreads();

    // ---- final sum across the 4 waves + store ----
    if (tid < 112) {
        const int kk = tid & 15;           // k within chunk
        const int m  = tid >> 4;           // 0..6
        const float s = red[0][kk][m] + red[1][kk][m]
                      + red[2][kk][m] + red[3][kk][m];
        const int nOut = (n + 1) % 7;      // final height roll
        out[((size_t)(g * 512 + kc * KC + kk) * 7 + nOut) * 7 + m] = s;
    }
}

extern "C" void kernel_launch(void* const* d_in, const int* in_sizes, int n_in,
                              void* d_out, int out_size, void* d_ws, size_t ws_size,
                              hipStream_t stream) {
    const float* x = (const float*)d_in[0];
    const float* w = (const float*)d_in[1];
    float* out = (float*)d_out;
    conv_one<<<dim3(NKC * 14), dim3(256), 0, stream>>>(x, w, out);
}